// Round 2
// baseline (2593.139 us; speedup 1.0000x reference)
//
#include <hip/hip_runtime.h>
#include <hip/hip_bf16.h>

#define FH 96
#define FW 96
#define NPOS (FH*FW)          // 9216
#define C 512
#define NA 9
#define NANCH (NPOS*NA)       // 82944
#define NPAD 131072           // 2^17 for bitonic
#define MAXOUT 1000
#define NMS_T 0.1f

typedef unsigned long long ull;
typedef short short8v __attribute__((ext_vector_type(8)));
typedef float f32x4 __attribute__((ext_vector_type(4)));

// dependent-chain-safe MFMA: D==C ("+v"), A/B 4-VGPR bf16x8
#define MFMA16(ACC, A, B) asm("v_mfma_f32_16x16x32_bf16 %0, %1, %2, %0" : "+v"(ACC) : "v"(A), "v"(B))

// ---------------- fp32 -> 3x bf16 split helpers (RNE) ----------------
__device__ __forceinline__ unsigned short bf16rne(float f) {
  unsigned u = __float_as_uint(f);
  return (unsigned short)((u + 0x7fffu + ((u >> 16) & 1u)) >> 16);
}
__device__ __forceinline__ float bf16tof(unsigned short h) {
  return __uint_as_float(((unsigned)h) << 16);
}
__device__ __forceinline__ void split3(float x, unsigned short& h, unsigned short& m, unsigned short& l) {
  h = bf16rne(x);
  float r1 = x - bf16tof(h);
  m = bf16rne(r1);
  float r2 = r1 - bf16tof(m);
  l = bf16rne(r2);
}

// ---------------- split feature: [9216][512] f32 -> 3 bf16 planes ----------------
__launch_bounds__(256)
__global__ void split_feat(const float* __restrict__ src,
                           unsigned short* __restrict__ hi,
                           unsigned short* __restrict__ mi,
                           unsigned short* __restrict__ lo) {
  const int i = (blockIdx.x * 256 + threadIdx.x) * 4;   // 4 floats per thread
  const float4 v = *(const float4*)(src + i);
  unsigned short h0,h1,h2,h3,m0,m1,m2,m3,l0,l1,l2,l3;
  split3(v.x,h0,m0,l0); split3(v.y,h1,m1,l1); split3(v.z,h2,m2,l2); split3(v.w,h3,m3,l3);
  *(ushort4*)(hi + i) = make_ushort4(h0,h1,h2,h3);
  *(ushort4*)(mi + i) = make_ushort4(m0,m1,m2,m3);
  *(ushort4*)(lo + i) = make_ushort4(l0,l1,l2,l3);
}

// ---------------- split + transpose W: [4608][512] f32 -> 3 bf16 planes [512][4608] ----------------
__launch_bounds__(256)
__global__ void split_w(const float* __restrict__ W,
                        unsigned short* __restrict__ hi,
                        unsigned short* __restrict__ mi,
                        unsigned short* __restrict__ lo) {
  __shared__ float tile[32][36];
  const int t = threadIdx.x;
  const int k0 = blockIdx.x * 32, n0 = blockIdx.y * 32;
  {
    const int kr = t >> 3, nc = (t & 7) * 4;
    const float4 v = *(const float4*)(W + (size_t)(k0 + kr) * C + n0 + nc);
    tile[kr][nc] = v.x; tile[kr][nc+1] = v.y; tile[kr][nc+2] = v.z; tile[kr][nc+3] = v.w;
  }
  __syncthreads();
  {
    const int nr = t >> 3, kc = (t & 7) * 4;
    unsigned short h[4], m[4], l[4];
    #pragma unroll
    for (int i = 0; i < 4; ++i) split3(tile[kc + i][nr], h[i], m[i], l[i]);
    const size_t off = (size_t)(n0 + nr) * 4608 + k0 + kc;
    *(ushort4*)(hi + off) = make_ushort4(h[0],h[1],h[2],h[3]);
    *(ushort4*)(mi + off) = make_ushort4(m[0],m[1],m[2],m[3]);
    *(ushort4*)(lo + off) = make_ushort4(l[0],l[1],l[2],l[3]);
  }
}

// ---------------- Conv 3x3 via MFMA bf16x3 (6-product split) ----------------
// GEMM: M=9216 (spatial), N=512 (co), K=4608 (tap*512+ci)
// Tile BM=128 x BN=64, BK=32, 256 threads = 4 waves (each wave: 32 rows x 64 cols)
__launch_bounds__(256)
__global__ void conv_mfma(const unsigned short* __restrict__ fH,
                          const unsigned short* __restrict__ fM,
                          const unsigned short* __restrict__ fL,
                          const unsigned short* __restrict__ wH,
                          const unsigned short* __restrict__ wM,
                          const unsigned short* __restrict__ wL,
                          const float* __restrict__ br,
                          float* __restrict__ xout) {
  __shared__ __align__(16) unsigned short As[3][128][40];  // [split][row][k] pad->2-way banks
  __shared__ __align__(16) unsigned short Bs[3][64][40];   // [split][n][k]
  const int tid = threadIdx.x;
  const int bm = blockIdx.y * 128, bn = blockIdx.x * 64;

  // A staging: 2 threads per row, each 16 ushorts (two uint4)
  const int ar = tid >> 1, ah = (tid & 1) * 16;
  const int p = bm + ar;
  const int py = p / FW, px = p % FW;
  // B staging: 4 threads per n-row, each 8 ushorts (one uint4)
  const int bnr = tid >> 2, bq = (tid & 3) * 8;
  // fragment ids
  const int wid = tid >> 6, lane = tid & 63;
  const int l15 = lane & 15, lk = (lane >> 4) * 8;
  const int wrow = wid * 32;

  f32x4 acc[2][4] = {};

  const unsigned short* fsp[3] = { fH, fM, fL };
  const unsigned short* wsp[3] = { wH, wM, wL };

  for (int kb = 0; kb < 144; ++kb) {
    const int t = kb >> 4, ci0 = (kb & 15) * 32;
    const int dy = t / 3 - 1, dx = t % 3 - 1;
    const int yy = py + dy, xx = px + dx;
    const bool avld = ((unsigned)yy < (unsigned)FH) && ((unsigned)xx < (unsigned)FW);
    const size_t abase = (size_t)(yy * FW + xx) * C + ci0 + ah;
    const size_t bbase = (size_t)(bn + bnr) * 4608 + kb * 32 + bq;

    uint4 aA[3][2];
    uint4 bB[3];
    #pragma unroll
    for (int s = 0; s < 3; ++s) {
      if (avld) {
        aA[s][0] = *(const uint4*)(fsp[s] + abase);
        aA[s][1] = *(const uint4*)(fsp[s] + abase + 8);
      } else {
        aA[s][0] = make_uint4(0,0,0,0);
        aA[s][1] = make_uint4(0,0,0,0);
      }
      bB[s] = *(const uint4*)(wsp[s] + bbase);
    }

    __syncthreads();   // previous iteration's LDS reads complete
    #pragma unroll
    for (int s = 0; s < 3; ++s) {
      *(uint4*)&As[s][ar][ah]     = aA[s][0];
      *(uint4*)&As[s][ar][ah + 8] = aA[s][1];
      *(uint4*)&Bs[s][bnr][bq]    = bB[s];
    }
    __syncthreads();

    short8v aF[3][2], bF[3][4];
    #pragma unroll
    for (int s = 0; s < 3; ++s) {
      #pragma unroll
      for (int fr = 0; fr < 2; ++fr)
        aF[s][fr] = *(const short8v*)&As[s][wrow + fr * 16 + l15][lk];
      #pragma unroll
      for (int fc = 0; fc < 4; ++fc)
        bF[s][fc] = *(const short8v*)&Bs[s][fc * 16 + l15][lk];
    }

    // 6 products: hh, hm, mh, hl, lh, mm — inner loop over 8 independent accs
    const int SA[6] = {0, 0, 1, 0, 2, 1};
    const int SB[6] = {0, 1, 0, 2, 0, 1};
    #pragma unroll
    for (int pмеждунар = 0; pмеждунар < 6; ++pмеждунар) {
      const int sa = SA[pмеждунар], sb = SB[pмеждунар];
      #pragma unroll
      for (int fr = 0; fr < 2; ++fr)
        #pragma unroll
        for (int fc = 0; fc < 4; ++fc)
          MFMA16(acc[fr][fc], aF[sa][fr], bF[sb][fc]);
    }
  }

  asm volatile("s_nop 7\ns_nop 7\ns_nop 7");  // MFMA write -> VALU read hazard

  #pragma unroll
  for (int fr = 0; fr < 2; ++fr) {
    #pragma unroll
    for (int fc = 0; fc < 4; ++fc) {
      const int col = bn + fc * 16 + l15;
      const float bias = br[col];
      #pragma unroll
      for (int r = 0; r < 4; ++r) {
        const int row = bm + wrow + fr * 16 + (lane >> 4) * 4 + r;
        xout[(size_t)row * C + col] = fmaxf(acc[fr][fc][r] + bias, 0.f);
      }
    }
  }
}

// ---------------- Head: 1x1 convs + sigmoid + bbox decode + sort keys ----------------
__launch_bounds__(256)
__global__ void head_kernel(const float* __restrict__ x,
                            const float* __restrict__ Wc, const float* __restrict__ bc,
                            const float* __restrict__ Wb, const float* __restrict__ bb,
                            const float* __restrict__ anchors, const int* __restrict__ im_size,
                            float* __restrict__ scores, float* __restrict__ props,
                            ull* __restrict__ keys) {
  const int a = blockIdx.x * 256 + threadIdx.x;
  if (a >= NANCH) { keys[a] = 0ull; return; }
  const int pos = a / NA, j = a - pos * NA;
  const float* xr = x + (size_t)pos * C;
  float accn = bc[j], accp = bc[j + NA];
  float d0 = bb[4*j], d1 = bb[4*j+1], d2 = bb[4*j+2], d3 = bb[4*j+3];
  for (int k = 0; k < C; ++k) {
    const float xv = xr[k];
    accn += xv * Wc[k * 18 + j];
    accp += xv * Wc[k * 18 + j + NA];
    const float4 wb = *(const float4*)(Wb + (size_t)k * 36 + 4 * j);
    d0 += xv * wb.x; d1 += xv * wb.y; d2 += xv * wb.z; d3 += xv * wb.w;
  }
  const float score = 1.0f / (1.0f + expf(accn - accp));
  const float4 anc = *(const float4*)(anchors + (size_t)4 * a);
  const float w  = anc.z - anc.x + 1.0f;
  const float h  = anc.w - anc.y + 1.0f;
  const float cx = anc.x + 0.5f * w;
  const float cy = anc.y + 0.5f * h;
  const float pcx = d0 * w + cx;
  const float pcy = d1 * h + cy;
  const float pw  = expf(d2) * w;
  const float ph  = expf(d3) * h;
  const float lim = (float)(*im_size - 1);
  float x1 = fminf(fmaxf(pcx - 0.5f * pw, 0.f), lim);
  float y1 = fminf(fmaxf(pcy - 0.5f * ph, 0.f), lim);
  float x2 = fminf(fmaxf(pcx + 0.5f * pw, 0.f), lim);
  float y2 = fminf(fmaxf(pcy + 0.5f * ph, 0.f), lim);
  *(float4*)(props + (size_t)4 * a) = make_float4(x1, y1, x2, y2);
  scores[a] = score;
  keys[a] = ((ull)__float_as_uint(score) << 32) | (unsigned)(~(unsigned)a);
}

// ---------------- Bitonic sort (descending), 2^17 elements ----------------
__launch_bounds__(1024)
__global__ void bitonic_local(ull* __restrict__ keys) {
  __shared__ ull s[4096];
  const int tid = threadIdx.x;
  const unsigned base = blockIdx.x * 4096u;
  for (int i = tid; i < 4096; i += 1024) s[i] = keys[base + i];
  __syncthreads();
  for (int k = 2; k <= 4096; k <<= 1) {
    for (int j = k >> 1; j > 0; j >>= 1) {
      for (int pr = tid; pr < 2048; pr += 1024) {
        const int i = ((pr / j) * 2 * j) + (pr % j);
        const int ixj = i + j;
        const bool descFirst = (((base + i) & (unsigned)k) == 0u);
        const ull av = s[i], bv = s[ixj];
        if (descFirst ? (av < bv) : (av > bv)) { s[i] = bv; s[ixj] = av; }
      }
      __syncthreads();
    }
  }
  for (int i = tid; i < 4096; i += 1024) keys[base + i] = s[i];
}

__launch_bounds__(256)
__global__ void bitonic_global(ull* __restrict__ keys, int k, int j) {
  const int pr = blockIdx.x * 256 + threadIdx.x;
  const int i = (pr / j) * 2 * j + (pr % j);
  const int ixj = i + j;
  const bool descFirst = ((i & k) == 0);
  const ull av = keys[i], bv = keys[ixj];
  if (descFirst ? (av < bv) : (av > bv)) { keys[i] = bv; keys[ixj] = av; }
}

__launch_bounds__(1024)
__global__ void bitonic_merge(ull* __restrict__ keys, int k) {
  __shared__ ull s[4096];
  const int tid = threadIdx.x;
  const unsigned base = blockIdx.x * 4096u;
  for (int i = tid; i < 4096; i += 1024) s[i] = keys[base + i];
  __syncthreads();
  const bool descFirst = ((base & (unsigned)k) == 0u);
  for (int j = 2048; j > 0; j >>= 1) {
    for (int pr = tid; pr < 2048; pr += 1024) {
      const int i = ((pr / j) * 2 * j) + (pr % j);
      const int ixj = i + j;
      const ull av = s[i], bv = s[ixj];
      if (descFirst ? (av < bv) : (av > bv)) { s[i] = bv; s[ixj] = av; }
    }
    __syncthreads();
  }
  for (int i = tid; i < 4096; i += 1024) keys[base + i] = s[i];
}

// ---------------- NMS: parallel prefilter + compaction + single-wave resolve ----------------
#define NCELL 48
#define CCAP 8
#define NMSCHUNK 2048
#define NCHUNKS 41   // 41*2048 = 83968 >= 82944 (tail keys invalid)

__launch_bounds__(1024)
__global__ void nms_kernel(const ull* __restrict__ keys,
                           const float* __restrict__ props,
                           int* __restrict__ kept_idx,
                           int* __restrict__ kept_count) {
  __shared__ float kx1[MAXOUT], ky1[MAXOUT], kx2[MAXOUT], ky2[MAXOUT], kar[MAXOUT];
  __shared__ float cb[NMSCHUNK][5];        // compacted alive boxes (x1,y1,x2,y2,area)
  __shared__ int   cidx[NMSCHUNK];
  __shared__ unsigned short cellent[NCELL * NCELL * CCAP];
  __shared__ unsigned char  cellcnt[NCELL * NCELL];
  __shared__ int s_kept, s_done;
  __shared__ int wcnt0[16], wcnt1[16];
  const int tid = threadIdx.x, wid = tid >> 6, lane = tid & 63;

  for (int i = tid; i < NCELL * NCELL; i += 1024) cellcnt[i] = 0;
  if (tid == 0) { s_kept = 0; s_done = 0; }
  __syncthreads();

  // suppressed-by-kept check via cell hash (exact; full-scan fallback on overflow)
  auto suppressed = [&](float x1, float y1, float x2, float y2, float ar, int kc) -> bool {
    const int gx0 = (int)(x1 * 0.03125f), gxe = (int)(x2 * 0.03125f);
    const int gy0 = (int)(y1 * 0.03125f), gye = (int)(y2 * 0.03125f);
    bool fb = false;
    for (int gy = gy0; gy <= gye && !fb; ++gy) {
      for (int gx = gx0; gx <= gxe; ++gx) {
        const int cell = gy * NCELL + gx;
        const int cnt = cellcnt[cell];
        if (cnt > CCAP) { fb = true; break; }
        for (int e = 0; e < cnt; ++e) {
          const int kk = cellent[cell * CCAP + e];
          const float ix1 = fmaxf(x1, kx1[kk]), iy1 = fmaxf(y1, ky1[kk]);
          const float ix2 = fminf(x2, kx2[kk]), iy2 = fminf(y2, ky2[kk]);
          const float inter = fmaxf(ix2 - ix1, 0.f) * fmaxf(iy2 - iy1, 0.f);
          const float iou = inter / (ar + kar[kk] - inter + 1e-8f);
          if (iou > NMS_T) return true;
        }
      }
    }
    if (fb) {
      for (int kk = 0; kk < kc; ++kk) {
        const float ix1 = fmaxf(x1, kx1[kk]), iy1 = fmaxf(y1, ky1[kk]);
        const float ix2 = fminf(x2, kx2[kk]), iy2 = fminf(y2, ky2[kk]);
        const float inter = fmaxf(ix2 - ix1, 0.f) * fmaxf(iy2 - iy1, 0.f);
        const float iou = inter / (ar + kar[kk] - inter + 1e-8f);
        if (iou > NMS_T) return true;
      }
    }
    return false;
  };

  for (int chunk = 0; chunk < NCHUNKS; ++chunk) {
    if (s_done) break;
    const int kcBase = s_kept;
    const int base = chunk * NMSCHUNK;

    // -------- load + prefilter 2 candidates per thread --------
    float x1a[2], y1a[2], x2a[2], y2a[2], ara[2];
    int ida[2];
    bool alive[2];
    #pragma unroll
    for (int c = 0; c < 2; ++c) {
      const int ci = base + c * 1024 + tid;
      const ull key = keys[ci];
      const bool valid = (key >> 32) != 0ull;
      const int idx = (int)(~(unsigned)(key & 0xFFFFFFFFull));
      bool alv = false;
      float x1 = 0, y1 = 0, x2 = 0, y2 = 0, ar = 0;
      if (valid) {
        const float4 b = *(const float4*)(props + ((size_t)idx << 2));
        x1 = b.x; y1 = b.y; x2 = b.z; y2 = b.w;
        ar = (x2 - x1) * (y2 - y1);
        alv = !suppressed(x1, y1, x2, y2, ar, kcBase);
      }
      x1a[c] = x1; y1a[c] = y1; x2a[c] = x2; y2a[c] = y2; ara[c] = ar;
      ida[c] = idx; alive[c] = alv;
    }
    const ull b0 = __ballot(alive[0]);
    const ull b1 = __ballot(alive[1]);
    if (lane == 0) { wcnt0[wid] = __popcll(b0); wcnt1[wid] = __popcll(b1); }
    __syncthreads();

    // -------- order-preserving compaction --------
    int tot0 = 0, pre0 = 0, pre1 = 0, tot1 = 0;
    for (int w = 0; w < 16; ++w) {
      if (w < wid) { pre0 += wcnt0[w]; pre1 += wcnt1[w]; }
      tot0 += wcnt0[w]; tot1 += wcnt1[w];
    }
    const ull ltmask = (lane == 0) ? 0ull : ((~0ull) >> (64 - lane));
    if (alive[0]) {
      const int o = pre0 + __popcll(b0 & ltmask);
      cb[o][0] = x1a[0]; cb[o][1] = y1a[0]; cb[o][2] = x2a[0]; cb[o][3] = y2a[0]; cb[o][4] = ara[0];
      cidx[o] = ida[0];
    }
    if (alive[1]) {
      const int o = tot0 + pre1 + __popcll(b1 & ltmask);
      cb[o][0] = x1a[1]; cb[o][1] = y1a[1]; cb[o][2] = x2a[1]; cb[o][3] = y2a[1]; cb[o][4] = ara[1];
      cidx[o] = ida[1];
    }
    const int n = tot0 + tot1;
    __syncthreads();

    // -------- single-wave serial resolution --------
    if (wid == 0) {
      int kc = kcBase;
      for (int g = 0; g < n && kc < MAXOUT; g += 64) {
        bool alv = (g + lane) < n;
        float x1 = 0, y1 = 0, x2 = 0, y2 = 0, ar = 0;
        int idx = -1;
        if (alv) {
          x1 = cb[g + lane][0]; y1 = cb[g + lane][1];
          x2 = cb[g + lane][2]; y2 = cb[g + lane][3]; ar = cb[g + lane][4];
          idx = cidx[g + lane];
          // delta-check vs boxes kept since chunk start
          for (int kk = kcBase; kk < kc && alv; ++kk) {
            const float ix1 = fmaxf(x1, kx1[kk]), iy1 = fmaxf(y1, ky1[kk]);
            const float ix2 = fminf(x2, kx2[kk]), iy2 = fminf(y2, ky2[kk]);
            const float inter = fmaxf(ix2 - ix1, 0.f) * fmaxf(iy2 - iy1, 0.f);
            const float iou = inter / (ar + kar[kk] - inter + 1e-8f);
            if (iou > NMS_T) alv = false;
          }
        }
        while (true) {
          const ull ball = __ballot(alv);
          if (ball == 0ull || kc >= MAXOUT) break;
          const int src = __ffsll((long long)ball) - 1;
          const float bx1 = __shfl(x1, src), by1 = __shfl(y1, src);
          const float bx2 = __shfl(x2, src), by2 = __shfl(y2, src);
          const float bar = __shfl(ar, src);
          if (lane == src) {
            kx1[kc] = x1; ky1[kc] = y1; kx2[kc] = x2; ky2[kc] = y2; kar[kc] = ar;
            kept_idx[kc] = idx;
            const int gx0 = (int)(x1 * 0.03125f), gxe = (int)(x2 * 0.03125f);
            const int gy0 = (int)(y1 * 0.03125f), gye = (int)(y2 * 0.03125f);
            for (int gy = gy0; gy <= gye; ++gy)
              for (int gx = gx0; gx <= gxe; ++gx) {
                const int cell = gy * NCELL + gx;
                const int cnt = cellcnt[cell];
                if (cnt < CCAP) {
                  cellent[cell * CCAP + cnt] = (unsigned short)kc;
                  cellcnt[cell] = (unsigned char)(cnt + 1);
                } else {
                  cellcnt[cell] = (unsigned char)(CCAP + 1);
                }
              }
            alv = false;
          }
          if (alv) {
            const float ix1 = fmaxf(x1, bx1), iy1 = fmaxf(y1, by1);
            const float ix2 = fminf(x2, bx2), iy2 = fminf(y2, by2);
            const float inter = fmaxf(ix2 - ix1, 0.f) * fmaxf(iy2 - iy1, 0.f);
            const float iou = inter / (ar + bar - inter + 1e-8f);
            if (iou > NMS_T) alv = false;
          }
          kc++;
        }
      }
      if (lane == 0) { s_kept = kc; if (kc >= MAXOUT) s_done = 1; }
    }
    __syncthreads();
  }
  if (tid == 0) *kept_count = s_kept;
}

// ---------------- Output assembly ----------------
__launch_bounds__(256)
__global__ void output_kernel(const int* __restrict__ kept_idx, const int* __restrict__ kept_count,
                              const float* __restrict__ props, const float* __restrict__ scores,
                              float* __restrict__ out) {
  const int k = blockIdx.x * 256 + threadIdx.x;
  if (k >= MAXOUT) return;
  const int kc = *kept_count;
  if (k < kc) {
    const int idx = kept_idx[k];
    const float4 b = *(const float4*)(props + ((size_t)idx << 2));
    out[k * 5 + 0] = 0.f;
    out[k * 5 + 1] = b.x;
    out[k * 5 + 2] = b.y;
    out[k * 5 + 3] = b.z;
    out[k * 5 + 4] = b.w;
    out[5 * MAXOUT + k] = scores[idx];
  } else {
    out[k * 5 + 0] = 0.f;
    out[k * 5 + 1] = -1.f;
    out[k * 5 + 2] = -1.f;
    out[k * 5 + 3] = -1.f;
    out[k * 5 + 4] = -1.f;
    out[5 * MAXOUT + k] = -1.f;
  }
}

extern "C" void kernel_launch(void* const* d_in, const int* in_sizes, int n_in,
                              void* d_out, int out_size, void* d_ws, size_t ws_size,
                              hipStream_t stream) {
  const float* feat    = (const float*)d_in[0];
  const float* anchors = (const float*)d_in[1];
  const float* Wr      = (const float*)d_in[2];
  const float* br      = (const float*)d_in[3];
  const float* Wc      = (const float*)d_in[4];
  const float* bc      = (const float*)d_in[5];
  const float* Wb      = (const float*)d_in[6];
  const float* bb      = (const float*)d_in[7];
  const int*   im      = (const int*)d_in[8];
  float* out = (float*)d_out;

  char* ws = (char*)d_ws;
  // workspace layout (~64.1 MB)
  float* x            = (float*)(ws);                               // 18,874,368 B
  unsigned short* fH  = (unsigned short*)(ws + 18874368);           //  9,437,184
  unsigned short* fM  = (unsigned short*)(ws + 28311552);
  unsigned short* fL  = (unsigned short*)(ws + 37748736);
  unsigned short* wH  = (unsigned short*)(ws + 47185920);           //  4,718,592
  unsigned short* wM  = (unsigned short*)(ws + 51904512);
  unsigned short* wL  = (unsigned short*)(ws + 56623104);
  float* scores       = (float*)(ws + 61341696);                    //    331,776
  float* props        = (float*)(ws + 61673472);                    //  1,327,104
  ull*   keys         = (ull*)  (ws + 63000576);                    //  1,048,576
  int*   kept_idx     = (int*)  (ws + 64049152);
  int*   kept_cnt     = (int*)  (ws + 64053248);

  split_feat<<<4608, 256, 0, stream>>>(feat, fH, fM, fL);
  split_w<<<dim3(144, 16), 256, 0, stream>>>(Wr, wH, wM, wL);
  conv_mfma<<<dim3(8, 72), 256, 0, stream>>>(fH, fM, fL, wH, wM, wL, br, x);
  head_kernel<<<512, 256, 0, stream>>>(x, Wc, bc, Wb, bb, anchors, im, scores, props, keys);

  bitonic_local<<<32, 1024, 0, stream>>>(keys);
  for (int k = 8192; k <= 131072; k <<= 1) {
    for (int j = k >> 1; j >= 4096; j >>= 1)
      bitonic_global<<<256, 256, 0, stream>>>(keys, k, j);
    bitonic_merge<<<32, 1024, 0, stream>>>(keys, k);
  }

  nms_kernel<<<1, 1024, 0, stream>>>(keys, props, kept_idx, kept_cnt);
  output_kernel<<<4, 256, 0, stream>>>(kept_idx, kept_cnt, props, scores, out);
}

// Round 3
// 1029.905 us; speedup vs baseline: 2.5178x; 2.5178x over previous
//
#include <hip/hip_runtime.h>
#include <hip/hip_bf16.h>

#define FH 96
#define FW 96
#define NPOS (FH*FW)          // 9216
#define C 512
#define NA 9
#define NANCH (NPOS*NA)       // 82944
#define NPAD 131072           // 2^17 for bitonic
#define MAXOUT 1000
#define NMS_T 0.1f
#define TTOP 8192             // bitmask-NMS candidate window
#define MW 128                // mask words per row (TTOP/64)
#define NCELL 48
#define CCAP 8

typedef unsigned long long ull;
typedef short short8v __attribute__((ext_vector_type(8)));
typedef float f32x4 __attribute__((ext_vector_type(4)));

// dependent-chain-safe MFMA: D==C ("+v"), A/B 4-VGPR bf16x8
#define MFMA16(ACC, A, B) asm("v_mfma_f32_16x16x32_bf16 %0, %1, %2, %0" : "+v"(ACC) : "v"(A), "v"(B))

// ---------------- fp32 -> 3x bf16 split helpers (RNE) ----------------
__device__ __forceinline__ unsigned short bf16rne(float f) {
  unsigned u = __float_as_uint(f);
  return (unsigned short)((u + 0x7fffu + ((u >> 16) & 1u)) >> 16);
}
__device__ __forceinline__ float bf16tof(unsigned short h) {
  return __uint_as_float(((unsigned)h) << 16);
}
__device__ __forceinline__ void split3(float x, unsigned short& h, unsigned short& m, unsigned short& l) {
  h = bf16rne(x);
  float r1 = x - bf16tof(h);
  m = bf16rne(r1);
  float r2 = r1 - bf16tof(m);
  l = bf16rne(r2);
}

// ---------------- split feature: [9216][512] f32 -> 3 bf16 planes ----------------
__launch_bounds__(256)
__global__ void split_feat(const float* __restrict__ src,
                           unsigned short* __restrict__ hi,
                           unsigned short* __restrict__ mi,
                           unsigned short* __restrict__ lo) {
  const int i = (blockIdx.x * 256 + threadIdx.x) * 4;
  const float4 v = *(const float4*)(src + i);
  unsigned short h0,h1,h2,h3,m0,m1,m2,m3,l0,l1,l2,l3;
  split3(v.x,h0,m0,l0); split3(v.y,h1,m1,l1); split3(v.z,h2,m2,l2); split3(v.w,h3,m3,l3);
  *(ushort4*)(hi + i) = make_ushort4(h0,h1,h2,h3);
  *(ushort4*)(mi + i) = make_ushort4(m0,m1,m2,m3);
  *(ushort4*)(lo + i) = make_ushort4(l0,l1,l2,l3);
}

// ---------------- split + transpose W: [4608][512] -> 3 bf16 planes [512][4608] ----------------
__launch_bounds__(256)
__global__ void split_w(const float* __restrict__ W,
                        unsigned short* __restrict__ hi,
                        unsigned short* __restrict__ mi,
                        unsigned short* __restrict__ lo) {
  __shared__ float tile[32][36];
  const int t = threadIdx.x;
  const int k0 = blockIdx.x * 32, n0 = blockIdx.y * 32;
  {
    const int kr = t >> 3, nc = (t & 7) * 4;
    const float4 v = *(const float4*)(W + (size_t)(k0 + kr) * C + n0 + nc);
    tile[kr][nc] = v.x; tile[kr][nc+1] = v.y; tile[kr][nc+2] = v.z; tile[kr][nc+3] = v.w;
  }
  __syncthreads();
  {
    const int nr = t >> 3, kc = (t & 7) * 4;
    unsigned short h[4], m[4], l[4];
    #pragma unroll
    for (int i = 0; i < 4; ++i) split3(tile[kc + i][nr], h[i], m[i], l[i]);
    const size_t off = (size_t)(n0 + nr) * 4608 + k0 + kc;
    *(ushort4*)(hi + off) = make_ushort4(h[0],h[1],h[2],h[3]);
    *(ushort4*)(mi + off) = make_ushort4(m[0],m[1],m[2],m[3]);
    *(ushort4*)(lo + off) = make_ushort4(l[0],l[1],l[2],l[3]);
  }
}

// ---------------- Conv 3x3 via MFMA bf16x3 (6-product split) ----------------
// GEMM: M=9216 (spatial), N=512 (co), K=4608. BM=128 BN=64 BK=32, 4 waves.
// Flat grid 576; col-group = bid%8 -> aligns with XCD round-robin so each
// XCD's L2 caches one 1.75MB B-panel.
__launch_bounds__(256)
__global__ void conv_mfma(const unsigned short* __restrict__ fH,
                          const unsigned short* __restrict__ fM,
                          const unsigned short* __restrict__ fL,
                          const unsigned short* __restrict__ wH,
                          const unsigned short* __restrict__ wM,
                          const unsigned short* __restrict__ wL,
                          const float* __restrict__ br,
                          float* __restrict__ xout) {
  __shared__ __align__(16) unsigned short As[3][128][36];  // pad 36 -> 4-way max on b128 reads
  __shared__ __align__(16) unsigned short Bs[3][64][36];
  const int tid = threadIdx.x;
  const int bid = blockIdx.x;
  const int bn = (bid & 7) * 64;        // XCD-aligned column group
  const int bm = (bid >> 3) * 128;

  const int ar = tid >> 1, ah = (tid & 1) * 16;
  const int p = bm + ar;
  const int py = p / FW, px = p % FW;
  const int bnr = tid >> 2, bq = (tid & 3) * 8;
  const int wid = tid >> 6, lane = tid & 63;
  const int l15 = lane & 15, lk = (lane >> 4) * 8;
  const int wrow = wid * 32;

  f32x4 acc[2][4] = {};

  const unsigned short* fsp[3] = { fH, fM, fL };
  const unsigned short* wsp[3] = { wH, wM, wL };

  for (int kb = 0; kb < 144; ++kb) {
    const int t = kb >> 4, ci0 = (kb & 15) * 32;
    const int dy = t / 3 - 1, dx = t % 3 - 1;
    const int yy = py + dy, xx = px + dx;
    const bool avld = ((unsigned)yy < (unsigned)FH) && ((unsigned)xx < (unsigned)FW);
    const size_t abase = (size_t)(yy * FW + xx) * C + ci0 + ah;
    const size_t bbase = (size_t)(bn + bnr) * 4608 + kb * 32 + bq;

    uint4 aA[3][2];
    uint4 bB[3];
    #pragma unroll
    for (int s = 0; s < 3; ++s) {
      if (avld) {
        aA[s][0] = *(const uint4*)(fsp[s] + abase);
        aA[s][1] = *(const uint4*)(fsp[s] + abase + 8);
      } else {
        aA[s][0] = make_uint4(0,0,0,0);
        aA[s][1] = make_uint4(0,0,0,0);
      }
      bB[s] = *(const uint4*)(wsp[s] + bbase);
    }

    __syncthreads();
    #pragma unroll
    for (int s = 0; s < 3; ++s) {
      *(uint4*)&As[s][ar][ah]     = aA[s][0];
      *(uint4*)&As[s][ar][ah + 8] = aA[s][1];
      *(uint4*)&Bs[s][bnr][bq]    = bB[s];
    }
    __syncthreads();

    short8v aF[3][2], bF[3][4];
    #pragma unroll
    for (int s = 0; s < 3; ++s) {
      #pragma unroll
      for (int fr = 0; fr < 2; ++fr)
        aF[s][fr] = *(const short8v*)&As[s][wrow + fr * 16 + l15][lk];
      #pragma unroll
      for (int fc = 0; fc < 4; ++fc)
        bF[s][fc] = *(const short8v*)&Bs[s][fc * 16 + l15][lk];
    }

    const int SA[6] = {0, 0, 1, 0, 2, 1};
    const int SB[6] = {0, 1, 0, 2, 0, 1};
    #pragma unroll
    for (int pr = 0; pr < 6; ++pr) {
      const int sa = SA[pr], sb = SB[pr];
      #pragma unroll
      for (int fr = 0; fr < 2; ++fr)
        #pragma unroll
        for (int fc = 0; fc < 4; ++fc)
          MFMA16(acc[fr][fc], aF[sa][fr], bF[sb][fc]);
    }
  }

  asm volatile("s_nop 7\ns_nop 7\ns_nop 7");

  #pragma unroll
  for (int fr = 0; fr < 2; ++fr) {
    #pragma unroll
    for (int fc = 0; fc < 4; ++fc) {
      const int col = bn + fc * 16 + l15;
      const float bias = br[col];
      #pragma unroll
      for (int r = 0; r < 4; ++r) {
        const int row = bm + wrow + fr * 16 + (lane >> 4) * 4 + r;
        xout[(size_t)row * C + col] = fmaxf(acc[fr][fc][r] + bias, 0.f);
      }
    }
  }
}

// ---------------- Head: 1x1 convs + sigmoid + bbox decode + sort keys ----------------
__launch_bounds__(256)
__global__ void head_kernel(const float* __restrict__ x,
                            const float* __restrict__ Wc, const float* __restrict__ bc,
                            const float* __restrict__ Wb, const float* __restrict__ bb,
                            const float* __restrict__ anchors, const int* __restrict__ im_size,
                            float* __restrict__ scores, float* __restrict__ props,
                            ull* __restrict__ keys) {
  const int a = blockIdx.x * 256 + threadIdx.x;
  if (a >= NANCH) { if (a < NPAD) keys[a] = 0ull; return; }
  const int pos = a / NA, j = a - pos * NA;
  const float* xr = x + (size_t)pos * C;
  float accn = bc[j], accp = bc[j + NA];
  float d0 = bb[4*j], d1 = bb[4*j+1], d2 = bb[4*j+2], d3 = bb[4*j+3];
  for (int k = 0; k < C; ++k) {
    const float xv = xr[k];
    accn += xv * Wc[k * 18 + j];
    accp += xv * Wc[k * 18 + j + NA];
    const float4 wb = *(const float4*)(Wb + (size_t)k * 36 + 4 * j);
    d0 += xv * wb.x; d1 += xv * wb.y; d2 += xv * wb.z; d3 += xv * wb.w;
  }
  const float score = 1.0f / (1.0f + expf(accn - accp));
  const float4 anc = *(const float4*)(anchors + (size_t)4 * a);
  const float w  = anc.z - anc.x + 1.0f;
  const float h  = anc.w - anc.y + 1.0f;
  const float cx = anc.x + 0.5f * w;
  const float cy = anc.y + 0.5f * h;
  const float pcx = d0 * w + cx;
  const float pcy = d1 * h + cy;
  const float pw  = expf(d2) * w;
  const float ph  = expf(d3) * h;
  const float lim = (float)(*im_size - 1);
  float x1 = fminf(fmaxf(pcx - 0.5f * pw, 0.f), lim);
  float y1 = fminf(fmaxf(pcy - 0.5f * ph, 0.f), lim);
  float x2 = fminf(fmaxf(pcx + 0.5f * pw, 0.f), lim);
  float y2 = fminf(fmaxf(pcy + 0.5f * ph, 0.f), lim);
  *(float4*)(props + (size_t)4 * a) = make_float4(x1, y1, x2, y2);
  scores[a] = score;
  keys[a] = ((ull)__float_as_uint(score) << 32) | (unsigned)(~(unsigned)a);
}

// ---------------- Bitonic sort (descending), 2^17 elements ----------------
__launch_bounds__(1024)
__global__ void bitonic_local(ull* __restrict__ keys) {
  __shared__ ull s[4096];
  const int tid = threadIdx.x;
  const unsigned base = blockIdx.x * 4096u;
  for (int i = tid; i < 4096; i += 1024) s[i] = keys[base + i];
  __syncthreads();
  for (int k = 2; k <= 4096; k <<= 1) {
    for (int j = k >> 1; j > 0; j >>= 1) {
      for (int pr = tid; pr < 2048; pr += 1024) {
        const int i = ((pr / j) * 2 * j) + (pr % j);
        const int ixj = i + j;
        const bool descFirst = (((base + i) & (unsigned)k) == 0u);
        const ull av = s[i], bv = s[ixj];
        if (descFirst ? (av < bv) : (av > bv)) { s[i] = bv; s[ixj] = av; }
      }
      __syncthreads();
    }
  }
  for (int i = tid; i < 4096; i += 1024) keys[base + i] = s[i];
}

// multi-level global step: handles j = 4096<<(L-1) .. 4096 for sort-step k=4096<<L
template<int L>
__launch_bounds__(256)
__global__ void bitonic_multi(ull* __restrict__ keys, int k) {
  const int tid = blockIdx.x * 256 + threadIdx.x;   // < NPAD >> L
  const int low = tid & 4095;
  const int high = tid >> 12;
  const int base = (high << (12 + L)) | low;
  ull e[1 << L];
  #pragma unroll
  for (int m = 0; m < (1 << L); ++m) e[m] = keys[base + (m << 12)];
  const bool desc = (base & k) == 0;
  #pragma unroll
  for (int l = L - 1; l >= 0; --l) {
    #pragma unroll
    for (int m = 0; m < (1 << L); ++m) {
      if (m & (1 << l)) continue;
      const int m2 = m | (1 << l);
      const ull a = e[m], b = e[m2];
      if (desc ? (a < b) : (a > b)) { e[m] = b; e[m2] = a; }
    }
  }
  #pragma unroll
  for (int m = 0; m < (1 << L); ++m) keys[base + (m << 12)] = e[m];
}

__launch_bounds__(1024)
__global__ void bitonic_merge(ull* __restrict__ keys, int k) {
  __shared__ ull s[4096];
  const int tid = threadIdx.x;
  const unsigned base = blockIdx.x * 4096u;
  for (int i = tid; i < 4096; i += 1024) s[i] = keys[base + i];
  __syncthreads();
  const bool descFirst = ((base & (unsigned)k) == 0u);
  for (int j = 2048; j > 0; j >>= 1) {
    for (int pr = tid; pr < 2048; pr += 1024) {
      const int i = ((pr / j) * 2 * j) + (pr % j);
      const int ixj = i + j;
      const ull av = s[i], bv = s[ixj];
      if (descFirst ? (av < bv) : (av > bv)) { s[i] = bv; s[ixj] = av; }
    }
    __syncthreads();
  }
  for (int i = tid; i < 4096; i += 1024) keys[base + i] = s[i];
}

// ---------------- gather sorted top-TTOP boxes ----------------
__launch_bounds__(256)
__global__ void gather_top(const ull* __restrict__ keys, const float* __restrict__ props,
                           float4* __restrict__ sbox4, float* __restrict__ sarea,
                           int* __restrict__ sidx) {
  const int t = blockIdx.x * 256 + threadIdx.x;
  const ull key = keys[t];
  const int idx = (int)(~(unsigned)(key & 0xFFFFFFFFull));
  const float4 b = *(const float4*)(props + ((size_t)idx << 2));
  sbox4[t] = b;
  sarea[t] = (b.z - b.x) * (b.w - b.y);
  sidx[t] = idx;
}

// ---------------- mask matrix: M[i][w] bit j = IoU(sorted i, sorted w*64+j) > T, j > i ----------------
__launch_bounds__(256)
__global__ void nms_mask(const float4* __restrict__ sbox4, const float* __restrict__ sarea,
                         ull* __restrict__ M) {
  const int wb = blockIdx.x;   // word-block (4 words = 256 cols)
  const int ib = blockIdx.y;   // row-block (64 rows)
  const int tid = threadIdx.x;
  const int r = tid & 63, ww = tid >> 6;
  const int i = ib * 64 + r;
  const int w = wb * 4 + ww;
  if (wb * 4 + 3 < ib) {              // fully below diagonal: zero-fill
    M[(size_t)i * MW + w] = 0ull;
    return;
  }
  __shared__ float4 jb[256];
  __shared__ float ja[256];
  jb[tid] = sbox4[wb * 256 + tid];
  ja[tid] = sarea[wb * 256 + tid];
  __syncthreads();
  if (w < (i >> 6)) { M[(size_t)i * MW + w] = 0ull; return; }
  const float4 bi = sbox4[i];
  const float ai = sarea[i];
  ull bits = 0;
  #pragma unroll 8
  for (int jj = 0; jj < 64; ++jj) {
    const float4 bj = jb[ww * 64 + jj];
    const float ix1 = fmaxf(bi.x, bj.x), iy1 = fmaxf(bi.y, bj.y);
    const float ix2 = fminf(bi.z, bj.z), iy2 = fminf(bi.w, bj.w);
    const float inter = fmaxf(ix2 - ix1, 0.f) * fmaxf(iy2 - iy1, 0.f);
    const float iou = inter / (ai + ja[ww * 64 + jj] - inter + 1e-8f);
    bits |= (ull)(iou > NMS_T) << jj;
  }
  if (w == (i >> 6)) {
    const int b = i & 63;
    bits &= (b == 63) ? 0ull : (~0ull << (b + 1));   // keep only j > i
  }
  M[(size_t)i * MW + w] = bits;
}

// ---------------- NMS scan: bitmask walk over top-TTOP, hash fallback beyond ----------------
__launch_bounds__(1024)
__global__ void nms_scan(const ull* __restrict__ M,
                         const ull* __restrict__ keys,
                         const float4* __restrict__ sbox4,
                         const float* __restrict__ sarea,
                         const int* __restrict__ sidx,
                         const float* __restrict__ props,
                         int* __restrict__ kept_idx,
                         int* __restrict__ kept_cnt) {
  __shared__ int   s_sel[MAXOUT];
  __shared__ float kx1[MAXOUT], ky1[MAXOUT], kx2[MAXOUT], ky2[MAXOUT], kar[MAXOUT];
  __shared__ int   cellcnt[NCELL * NCELL];
  __shared__ unsigned short cellent[NCELL * NCELL * CCAP];
  __shared__ float cb[2048][5];
  __shared__ int   cidx[2048];
  __shared__ int   s_kc;
  __shared__ int   wcnt0[16], wcnt1[16];
  const int tid = threadIdx.x, wid = tid >> 6, lane = tid & 63;

  // ======== Phase A: serial bitmask scan (wave 0 only) ========
  if (tid < 64) {
    ull rm0 = 0, rm1 = 0;       // lane owns removed words 2*lane, 2*lane+1
    int kc = 0;
    for (int g = 0; g < MW && kc < MAXOUT; ++g) {
      const ull wg = __shfl((g & 1) ? rm1 : rm0, g >> 1);
      ull w = ~wg;
      while (w && kc < MAXOUT) {
        int bs[4]; int nb = 0;
        { ull wb = w;
          #pragma unroll
          for (int t = 0; t < 4; ++t) {
            bs[t] = wb ? (__ffsll((long long)wb) - 1) : 0;
            if (wb) { ++nb; wb &= wb - 1; }
          }
        }
        ulonglong2 r[4];
        #pragma unroll
        for (int t = 0; t < 4; ++t) {
          const int bb = (t < nb) ? bs[t] : bs[0];
          r[t] = *(const ulonglong2*)(M + (size_t)(g * 64 + bb) * MW + 2 * lane);
        }
        #pragma unroll
        for (int t = 0; t < 4; ++t) {
          if (t < nb && kc < MAXOUT) {
            const int b = bs[t];
            if ((w >> b) & 1ull) {
              if (lane == 0) s_sel[kc] = g * 64 + b;
              rm0 |= r[t].x; rm1 |= r[t].y;
              const ull rowg = __shfl((g & 1) ? r[t].y : r[t].x, g >> 1);
              w &= ~rowg;
              w &= ~(1ull << b);
              ++kc;
            }
          }
        }
      }
    }
    if (lane == 0) s_kc = kc;
  }
  for (int i = tid; i < NCELL * NCELL; i += 1024) cellcnt[i] = 0;
  __syncthreads();

  const int kc0 = s_kc;
  // ======== fill kept arrays + hash (parallel) ========
  for (int k = tid; k < kc0; k += 1024) {
    const int i = s_sel[k];
    const float4 b = sbox4[i];
    kx1[k] = b.x; ky1[k] = b.y; kx2[k] = b.z; ky2[k] = b.w;
    kar[k] = sarea[i];
    kept_idx[k] = sidx[i];
    if (kc0 < MAXOUT) {
      const int gx0 = (int)(b.x * 0.03125f), gxe = (int)(b.z * 0.03125f);
      const int gy0 = (int)(b.y * 0.03125f), gye = (int)(b.w * 0.03125f);
      for (int gy = gy0; gy <= gye; ++gy)
        for (int gx = gx0; gx <= gxe; ++gx) {
          const int cell = gy * NCELL + gx;
          const int o = atomicAdd(&cellcnt[cell], 1);
          if (o < CCAP) cellent[cell * CCAP + o] = (unsigned short)k;
        }
    }
  }
  __syncthreads();

  // ======== Phase C: hash-prefiltered chunks over [TTOP, NANCH) ========
  if (kc0 < MAXOUT) {
    for (int chunk = 0; chunk < 37; ++chunk) {
      __syncthreads();
      const int kcBase = s_kc;
      if (kcBase >= MAXOUT) break;
      const int base = TTOP + chunk * 2048;

      float x1a[2], y1a[2], x2a[2], y2a[2], ara[2];
      int ida[2]; bool alive[2];
      #pragma unroll
      for (int c = 0; c < 2; ++c) {
        const int ci = base + c * 1024 + tid;
        const ull key = keys[ci];
        const bool valid = (key >> 32) != 0ull;
        const int idx = (int)(~(unsigned)(key & 0xFFFFFFFFull));
        bool alv = false;
        float x1 = 0, y1 = 0, x2 = 0, y2 = 0, ar = 0;
        if (valid) {
          const float4 b = *(const float4*)(props + ((size_t)idx << 2));
          x1 = b.x; y1 = b.y; x2 = b.z; y2 = b.w;
          ar = (x2 - x1) * (y2 - y1);
          // hash check, fixed trip counts (pipelined)
          bool sup = false, fb = false;
          const int gx0 = (int)(x1 * 0.03125f), gxe = (int)(x2 * 0.03125f);
          const int gy0 = (int)(y1 * 0.03125f), gye = (int)(y2 * 0.03125f);
          for (int gy = gy0; gy <= gye; ++gy)
            for (int gx = gx0; gx <= gxe; ++gx) {
              const int cell = gy * NCELL + gx;
              int cnt = cellcnt[cell];
              fb |= (cnt > CCAP);
              cnt = min(cnt, CCAP);
              for (int e = 0; e < cnt; ++e) {
                const int kk = cellent[cell * CCAP + e];
                const float ix1 = fmaxf(x1, kx1[kk]), iy1 = fmaxf(y1, ky1[kk]);
                const float ix2 = fminf(x2, kx2[kk]), iy2 = fminf(y2, ky2[kk]);
                const float inter = fmaxf(ix2 - ix1, 0.f) * fmaxf(iy2 - iy1, 0.f);
                sup |= (inter / (ar + kar[kk] - inter + 1e-8f) > NMS_T);
              }
            }
          if (fb && !sup) {
            for (int kk = 0; kk < kcBase; ++kk) {
              const float ix1 = fmaxf(x1, kx1[kk]), iy1 = fmaxf(y1, ky1[kk]);
              const float ix2 = fminf(x2, kx2[kk]), iy2 = fminf(y2, ky2[kk]);
              const float inter = fmaxf(ix2 - ix1, 0.f) * fmaxf(iy2 - iy1, 0.f);
              sup |= (inter / (ar + kar[kk] - inter + 1e-8f) > NMS_T);
            }
          }
          alv = !sup;
        }
        x1a[c] = x1; y1a[c] = y1; x2a[c] = x2; y2a[c] = y2; ara[c] = ar;
        ida[c] = idx; alive[c] = alv;
      }
      const ull b0 = __ballot(alive[0]);
      const ull b1 = __ballot(alive[1]);
      if (lane == 0) { wcnt0[wid] = __popcll(b0); wcnt1[wid] = __popcll(b1); }
      __syncthreads();

      int tot0 = 0, pre0 = 0, pre1 = 0, tot1 = 0;
      for (int w = 0; w < 16; ++w) {
        if (w < wid) { pre0 += wcnt0[w]; pre1 += wcnt1[w]; }
        tot0 += wcnt0[w]; tot1 += wcnt1[w];
      }
      const ull ltmask = (lane == 0) ? 0ull : ((~0ull) >> (64 - lane));
      if (alive[0]) {
        const int o = pre0 + __popcll(b0 & ltmask);
        cb[o][0] = x1a[0]; cb[o][1] = y1a[0]; cb[o][2] = x2a[0]; cb[o][3] = y2a[0]; cb[o][4] = ara[0];
        cidx[o] = ida[0];
      }
      if (alive[1]) {
        const int o = tot0 + pre1 + __popcll(b1 & ltmask);
        cb[o][0] = x1a[1]; cb[o][1] = y1a[1]; cb[o][2] = x2a[1]; cb[o][3] = y2a[1]; cb[o][4] = ara[1];
        cidx[o] = ida[1];
      }
      const int n = tot0 + tot1;
      __syncthreads();

      if (tid < 64) {
        int kc = kcBase;
        for (int g = 0; g < n && kc < MAXOUT; g += 64) {
          bool alv = (g + lane) < n;
          float x1 = 0, y1 = 0, x2 = 0, y2 = 0, ar = 0;
          int idx = -1;
          if (alv) {
            x1 = cb[g + lane][0]; y1 = cb[g + lane][1];
            x2 = cb[g + lane][2]; y2 = cb[g + lane][3]; ar = cb[g + lane][4];
            idx = cidx[g + lane];
            bool sup = false;
            for (int kk = kcBase; kk < kc; ++kk) {   // fixed trip, pipelined
              const float ix1 = fmaxf(x1, kx1[kk]), iy1 = fmaxf(y1, ky1[kk]);
              const float ix2 = fminf(x2, kx2[kk]), iy2 = fminf(y2, ky2[kk]);
              const float inter = fmaxf(ix2 - ix1, 0.f) * fmaxf(iy2 - iy1, 0.f);
              sup |= (inter / (ar + kar[kk] - inter + 1e-8f) > NMS_T);
            }
            alv = alv && !sup;
          }
          while (true) {
            const ull ball = __ballot(alv);
            if (ball == 0ull || kc >= MAXOUT) break;
            const int src = __ffsll((long long)ball) - 1;
            const float bx1 = __shfl(x1, src), by1 = __shfl(y1, src);
            const float bx2 = __shfl(x2, src), by2 = __shfl(y2, src);
            const float bar = __shfl(ar, src);
            if (lane == src) {
              kx1[kc] = x1; ky1[kc] = y1; kx2[kc] = x2; ky2[kc] = y2; kar[kc] = ar;
              kept_idx[kc] = idx;
              const int gx0 = (int)(x1 * 0.03125f), gxe = (int)(x2 * 0.03125f);
              const int gy0 = (int)(y1 * 0.03125f), gye = (int)(y2 * 0.03125f);
              for (int gy = gy0; gy <= gye; ++gy)
                for (int gx = gx0; gx <= gxe; ++gx) {
                  const int cell = gy * NCELL + gx;
                  const int o = cellcnt[cell];
                  if (o < CCAP) cellent[cell * CCAP + o] = (unsigned short)kc;
                  cellcnt[cell] = o + 1;
                }
              alv = false;
            }
            if (alv) {
              const float ix1 = fmaxf(x1, bx1), iy1 = fmaxf(y1, by1);
              const float ix2 = fminf(x2, bx2), iy2 = fminf(y2, by2);
              const float inter = fmaxf(ix2 - ix1, 0.f) * fmaxf(iy2 - iy1, 0.f);
              if (inter / (ar + bar - inter + 1e-8f) > NMS_T) alv = false;
            }
            kc++;
          }
        }
        if (lane == 0) s_kc = kc;
      }
    }
  }
  __syncthreads();
  if (tid == 0) *kept_cnt = s_kc;
}

// ---------------- Output assembly ----------------
__launch_bounds__(256)
__global__ void output_kernel(const int* __restrict__ kept_idx, const int* __restrict__ kept_count,
                              const float* __restrict__ props, const float* __restrict__ scores,
                              float* __restrict__ out) {
  const int k = blockIdx.x * 256 + threadIdx.x;
  if (k >= MAXOUT) return;
  const int kc = *kept_count;
  if (k < kc) {
    const int idx = kept_idx[k];
    const float4 b = *(const float4*)(props + ((size_t)idx << 2));
    out[k * 5 + 0] = 0.f;
    out[k * 5 + 1] = b.x;
    out[k * 5 + 2] = b.y;
    out[k * 5 + 3] = b.z;
    out[k * 5 + 4] = b.w;
    out[5 * MAXOUT + k] = scores[idx];
  } else {
    out[k * 5 + 0] = 0.f;
    out[k * 5 + 1] = -1.f;
    out[k * 5 + 2] = -1.f;
    out[k * 5 + 3] = -1.f;
    out[k * 5 + 4] = -1.f;
    out[5 * MAXOUT + k] = -1.f;
  }
}

extern "C" void kernel_launch(void* const* d_in, const int* in_sizes, int n_in,
                              void* d_out, int out_size, void* d_ws, size_t ws_size,
                              hipStream_t stream) {
  const float* feat    = (const float*)d_in[0];
  const float* anchors = (const float*)d_in[1];
  const float* Wr      = (const float*)d_in[2];
  const float* br      = (const float*)d_in[3];
  const float* Wc      = (const float*)d_in[4];
  const float* bc      = (const float*)d_in[5];
  const float* Wb      = (const float*)d_in[6];
  const float* bb      = (const float*)d_in[7];
  const int*   im      = (const int*)d_in[8];
  float* out = (float*)d_out;

  char* ws = (char*)d_ws;
  // layout (max offset 64,049,152 — within proven ws capacity)
  float* x            = (float*)(ws);                     // 18,874,368
  ull*   M            = (ull*)(ws);                       // 8,388,608 (reuses x after head)
  unsigned short* fH  = (unsigned short*)(ws + 18874368); // 9,437,184 (reused below after conv)
  unsigned short* fM  = (unsigned short*)(ws + 28311552);
  unsigned short* fL  = (unsigned short*)(ws + 37748736);
  unsigned short* wH  = (unsigned short*)(ws + 47185920);
  unsigned short* wM  = (unsigned short*)(ws + 51904512);
  unsigned short* wL  = (unsigned short*)(ws + 56623104);
  float* scores       = (float*)(ws + 61341696);          // 331,776
  float* props        = (float*)(ws + 61673472);          // 1,327,104
  ull*   keys         = (ull*)  (ws + 63000576);          // 1,048,576 -> ends 64,049,152
  // overlays on dead fH region (fH dead after conv_mfma):
  float4* sbox4       = (float4*)(ws + 18874368);         // 131,072
  float*  sarea       = (float*) (ws + 19005440);         // 32,768
  int*    sidx        = (int*)   (ws + 19038208);         // 32,768
  int*    kept_idx    = (int*)   (ws + 19070976);         // 4,096
  int*    kept_cnt    = (int*)   (ws + 19075072);         // 4

  split_feat<<<4608, 256, 0, stream>>>(feat, fH, fM, fL);
  split_w<<<dim3(144, 16), 256, 0, stream>>>(Wr, wH, wM, wL);
  conv_mfma<<<576, 256, 0, stream>>>(fH, fM, fL, wH, wM, wL, br, x);
  head_kernel<<<512, 256, 0, stream>>>(x, Wc, bc, Wb, bb, anchors, im, scores, props, keys);

  bitonic_local<<<32, 1024, 0, stream>>>(keys);
  bitonic_multi<1><<<256, 256, 0, stream>>>(keys, 8192);
  bitonic_merge<<<32, 1024, 0, stream>>>(keys, 8192);
  bitonic_multi<2><<<128, 256, 0, stream>>>(keys, 16384);
  bitonic_merge<<<32, 1024, 0, stream>>>(keys, 16384);
  bitonic_multi<3><<<64, 256, 0, stream>>>(keys, 32768);
  bitonic_merge<<<32, 1024, 0, stream>>>(keys, 32768);
  bitonic_multi<4><<<32, 256, 0, stream>>>(keys, 65536);
  bitonic_merge<<<32, 1024, 0, stream>>>(keys, 65536);
  bitonic_multi<5><<<16, 256, 0, stream>>>(keys, 131072);
  bitonic_merge<<<32, 1024, 0, stream>>>(keys, 131072);

  gather_top<<<32, 256, 0, stream>>>(keys, props, sbox4, sarea, sidx);
  nms_mask<<<dim3(32, 128), 256, 0, stream>>>(sbox4, sarea, M);
  nms_scan<<<1, 1024, 0, stream>>>(M, keys, sbox4, sarea, sidx, props, kept_idx, kept_cnt);
  output_kernel<<<4, 256, 0, stream>>>(kept_idx, kept_cnt, props, scores, out);
}